// Round 3
// baseline (405.995 us; speedup 1.0000x reference)
//
#include <hip/hip_runtime.h>
#include <math.h>

// FourierCrossAttention, MI355X. Round 6: revert make_hilo8 to verified RNE
// bit-twiddle (cvt_pk path truncates -> 51x accuracy loss, R2 post-mortem).
// Keep k_dft software pipeline (ping-pong raw-f32 prefetch, tables first).
// B=32 H=8 E=64 M=64 O=64 L=1024.
//
// ws layout:
//   bytes [0, 1MB): bf16 twiddle tables in MFMA B-fragment layout (hi/lo)
//   floats from 262144: as before.
#define OFF_WTR   262144u   // wT[h][x][e][o]  2097152
#define OFF_WTI   2359296u
#define OFF_XQR   4456448u  // Xq [b][h][e][m] 1048576
#define OFF_XQI   5505024u
#define OFF_XKR   6553600u
#define OFF_XKI   7602176u
#define OFF_UR    8650752u  // u  [h][x][b][e] 1048576
#define OFF_UI    9699328u
#define OFF_YR    10747904u // xqkvw [h][x][b][o] 1048576
#define OFF_YI    11796480u

#define PI_F 3.14159265358979323846f

typedef __attribute__((ext_vector_type(8))) short bf16x8;
typedef __attribute__((ext_vector_type(4))) float f32x4;
typedef __attribute__((ext_vector_type(4))) unsigned int u32x4;

__device__ inline unsigned short f2bf(float f) {
    unsigned u = __float_as_uint(f);
    unsigned r = u + 0x7FFFu + ((u >> 16) & 1u);
    return (unsigned short)(r >> 16);
}
__device__ inline float bf2f(unsigned short h) {
    return __uint_as_float(((unsigned)h) << 16);
}
// Verified RNE hi/lo split (absmax 7.3e-12 in baseline). Do NOT replace with
// v_cvt_pk_bf16_f32: it does not round-to-nearest here (R2: 51x error).
__device__ inline void make_hilo8(const float* s, bf16x8& h, bf16x8& l) {
#pragma unroll
    for (int j = 0; j < 8; ++j) {
        unsigned short hb = f2bf(s[j]);
        h[j] = (short)hb;
        l[j] = (short)f2bf(s[j] - bf2f(hb));
    }
}
__device__ inline bf16x8 neg8(bf16x8 v) {
    u32x4 u = __builtin_bit_cast(u32x4, v);
#pragma unroll
    for (int p = 0; p < 4; ++p) u[p] ^= 0x80008000u;
    return __builtin_bit_cast(bf16x8, u);
}
__device__ inline float twval(int m, int t, bool neg_sin) {
    int r = (m * t) & 1023;
    float ang = (float)r * (2.0f * PI_F / 1024.0f);
    float s, c;
    sincosf(ang, &s, &c);
    return neg_sin ? -s : c;
}

// 3-pass split-bf16 MFMA: acc += (Ah+Al)*(Bh+Bl) approx
#define MFMA3(AH, AL, BH, BL, ACC)                                          \
    ACC = __builtin_amdgcn_mfma_f32_16x16x32_bf16(AH, BH, ACC, 0, 0, 0);    \
    ACC = __builtin_amdgcn_mfma_f32_16x16x32_bf16(AH, BL, ACC, 0, 0, 0);    \
    ACC = __builtin_amdgcn_mfma_f32_16x16x32_bf16(AL, BH, ACC, 0, 0, 0);

// ---------------- twiddle tables in MFMA B-fragment layout, split hi/lo -----
__global__ void k_tables(unsigned short* __restrict__ tab) {
    int idx = blockIdx.x * 256 + threadIdx.x;   // 131072 entries each table
    {
        int j = idx & 7, lane = (idx >> 3) & 63, nt = (idx >> 9) & 7, kt = idx >> 12;
        int k = kt * 32 + ((lane >> 4) << 3) + j;       // t (K dim)
        int n = nt * 16 + (lane & 15);                  // col in [0,128)
        float v = twval(n & 63, k, n >= 64);
        unsigned short hb = f2bf(v);
        tab[idx] = hb;
        tab[131072 + idx] = f2bf(v - bf2f(hb));
    }
    {
        int j = idx & 7, lane = (idx >> 3) & 63, ks = (idx >> 9) & 3, nt = idx >> 11;
        int kap = ks * 32 + ((lane >> 4) << 3) + j;     // kappa in [0,128)
        int t = nt * 16 + (lane & 15);
        float v = twval(kap & 63, t, kap >= 64);
        unsigned short hb = f2bf(v);
        tab[262144 + idx] = hb;
        tab[393216 + idx] = f2bf(v - bf2f(hb));
    }
}

// ---------------- transpose weights [h][e][o][x] -> [h][x][e][o] ------------
__global__ __launch_bounds__(256) void k_wt(const float* __restrict__ wr,
                                            const float* __restrict__ wi,
                                            float* __restrict__ ws) {
    __shared__ float tile[64 * 65];
    int he = blockIdx.x;            // h*64+e
    int h = he >> 6, e = he & 63;
    const float* srcs[2] = { wr + (size_t)he * 4096, wi + (size_t)he * 4096 };
    float* dsts[2] = { ws + OFF_WTR, ws + OFF_WTI };
    for (int p = 0; p < 2; ++p) {
        __syncthreads();
        {
            int x = threadIdx.x & 63, orow = threadIdx.x >> 6;
            for (int i = 0; i < 16; ++i) {
                int o = orow * 16 + i;
                tile[o * 65 + x] = srcs[p][o * 64 + x];
            }
        }
        __syncthreads();
        {
            int o = threadIdx.x & 63, xrow = threadIdx.x >> 6;
            for (int i = 0; i < 16; ++i) {
                int x = xrow * 16 + i;
                dsts[p][(((size_t)h * 64 + x) * 64 + e) * 64 + o] = tile[o * 65 + x];
            }
        }
    }
}

// ---------------- DFT via MFMA, barrier-free pipelined K-loop ---------------
// grid 512: src*256 + bh. 512 threads, 8 waves = 2 khalf x 2 mhalf x 2 nhalf.
// A-frags: raw f32 prefetched one kc ahead (ping-pong f0/f1); twiddle table
// loads for the CURRENT kc issue FIRST so the vmcnt in-order drain for the
// MFMAs does not wait on the prefetch.
#define LOADF(BUF, KC)                                                        \
    do {                                                                      \
        int tb_ = kh * 512 + (KC) * 64;                                       \
        _Pragma("unroll") for (int mt_ = 0; mt_ < 2; ++mt_) {                 \
            int e_ = mh * 32 + mt_ * 16 + (lane & 15);                        \
            _Pragma("unroll") for (int k2_ = 0; k2_ < 2; ++k2_) {             \
                int t0_ = tb_ + k2_ * 32 + (lane >> 4) * 8;                   \
                _Pragma("unroll") for (int j_ = 0; j_ < 8; ++j_) {            \
                    BUF[mt_][k2_][j_] =                                       \
                        A[(((size_t)b * 1024 + t0_ + j_) * 8 + h) * 64 + e_]; \
                }                                                             \
            }                                                                 \
        }                                                                     \
    } while (0)

#define ROUND(CUR, NXT, KC, DO_PRE)                                           \
    {                                                                         \
        bf16x8 tbh_[2][4], tbl_[2][4];                                        \
        _Pragma("unroll") for (int k2_ = 0; k2_ < 2; ++k2_) {                 \
            int ktile_ = kh * 16 + (KC) * 2 + k2_;                            \
            _Pragma("unroll") for (int ntl_ = 0; ntl_ < 4; ++ntl_) {          \
                int nt_ = nh * 4 + ntl_;                                      \
                size_t off_ = (((size_t)ktile_ * 8 + nt_) * 64 + lane) * 8;   \
                tbh_[k2_][ntl_] = *(const bf16x8*)(BDH + off_);               \
                tbl_[k2_][ntl_] = *(const bf16x8*)(BDL + off_);               \
            }                                                                 \
        }                                                                     \
        if (DO_PRE) LOADF(NXT, (KC) + 1);                                     \
        bf16x8 ah_[2][2], al_[2][2];                                          \
        _Pragma("unroll") for (int mt_ = 0; mt_ < 2; ++mt_) {                 \
            _Pragma("unroll") for (int k2_ = 0; k2_ < 2; ++k2_) {             \
                make_hilo8(CUR[mt_][k2_], ah_[mt_][k2_], al_[mt_][k2_]);      \
            }                                                                 \
        }                                                                     \
        _Pragma("unroll") for (int k2_ = 0; k2_ < 2; ++k2_) {                 \
            _Pragma("unroll") for (int ntl_ = 0; ntl_ < 4; ++ntl_) {          \
                _Pragma("unroll") for (int mt_ = 0; mt_ < 2; ++mt_) {         \
                    MFMA3(ah_[mt_][k2_], al_[mt_][k2_],                       \
                          tbh_[k2_][ntl_], tbl_[k2_][ntl_], acc[mt_][ntl_]);  \
                }                                                             \
            }                                                                 \
        }                                                                     \
    }

__global__ __launch_bounds__(512, 4) void k_dft(const float* __restrict__ q,
                                                const float* __restrict__ kk,
                                                float* __restrict__ ws) {
    int blk = blockIdx.x;
    int src = blk >> 8;
    int bhi = blk & 255;
    int b = bhi >> 3, h = bhi & 7;
    const float* A = src ? kk : q;
    const unsigned short* BDH = (const unsigned short*)ws;
    const unsigned short* BDL = BDH + 131072;

    int tid = threadIdx.x;
    int lane = tid & 63, wv = tid >> 6;
    int kh = wv & 1, mh = (wv >> 1) & 1, nh = wv >> 2;

    f32x4 acc[2][4];
#pragma unroll
    for (int a = 0; a < 2; ++a)
#pragma unroll
        for (int c = 0; c < 4; ++c) acc[a][c] = (f32x4){0.f, 0.f, 0.f, 0.f};

    float f0[2][2][8], f1[2][2][8];
    LOADF(f0, 0);
    ROUND(f0, f1, 0, 1)
    ROUND(f1, f0, 1, 1)
    ROUND(f0, f1, 2, 1)
    ROUND(f1, f0, 3, 1)
    ROUND(f0, f1, 4, 1)
    ROUND(f1, f0, 5, 1)
    ROUND(f0, f1, 6, 1)
    ROUND(f1, f0, 7, 0)

    // khalf reduction through LDS (conflict-free [reg][lane] layout)
    __shared__ float red[8192];
    int pair = wv >> 1;   // mh + 2*nh
    if (kh == 1) {
#pragma unroll
        for (int mt = 0; mt < 2; ++mt)
#pragma unroll
            for (int ntl = 0; ntl < 4; ++ntl)
#pragma unroll
                for (int r = 0; r < 4; ++r)
                    red[pair * 2048 + ((mt * 4 + ntl) * 4 + r) * 64 + lane] = acc[mt][ntl][r];
    }
    __syncthreads();
    if (kh == 0) {
        float* outR = ws + (src ? OFF_XKR : OFF_XQR) + (size_t)bhi * 4096;
        float* outI = ws + (src ? OFF_XKI : OFF_XQI) + (size_t)bhi * 4096;
#pragma unroll
        for (int mt = 0; mt < 2; ++mt)
#pragma unroll
            for (int ntl = 0; ntl < 4; ++ntl) {
#pragma unroll
                for (int r = 0; r < 4; ++r)
                    acc[mt][ntl][r] += red[pair * 2048 + ((mt * 4 + ntl) * 4 + r) * 64 + lane];
                int n = (nh * 4 + ntl) * 16 + (lane & 15);
                float* dst = (n < 64) ? (outR + n) : (outI + (n - 64));
                int erow0 = mh * 32 + mt * 16 + (lane >> 4) * 4;
#pragma unroll
                for (int r = 0; r < 4; ++r)
                    dst[(erow0 + r) * 64] = acc[mt][ntl][r];
            }
    }
}

// ---------------- attn: S = Xq^T Xk, tanh, u = S~ Xk^T, all MFMA ------------
// grid 256 = (b,h); 256 threads, 4 waves; wave owns 16 rows (x).
__global__ __launch_bounds__(256, 1) void k_attn(float* __restrict__ ws) {
    __shared__ float sKR[64 * 65], sKI[64 * 65];
    __shared__ float sQR[64 * 65], sQI[64 * 65];   // later reused for S~
    int bhi = blockIdx.x;
    int b = bhi >> 3, h = bhi & 7;
    int tid = threadIdx.x, lane = tid & 63, wv = tid >> 6;
    const float* XqR = ws + OFF_XQR + (size_t)bhi * 4096;
    const float* XqI = ws + OFF_XQI + (size_t)bhi * 4096;
    const float* XkR = ws + OFF_XKR + (size_t)bhi * 4096;
    const float* XkI = ws + OFF_XKI + (size_t)bhi * 4096;
    for (int i = tid; i < 4096; i += 256) {
        int e = i >> 6, m = i & 63;
        sQR[e * 65 + m] = XqR[i];
        sQI[e * 65 + m] = XqI[i];
        sKR[e * 65 + m] = XkR[i];
        sKI[e * 65 + m] = XkI[i];
    }
    __syncthreads();

    // ---- GEMM1 A-frags: A[m=x][k=e] = Xq[e][x]
    int x = wv * 16 + (lane & 15);
    bf16x8 aRh[2], aRl[2], aIh[2], aIl[2], aInh[2], aInl[2];
#pragma unroll
    for (int k2 = 0; k2 < 2; ++k2) {
        float fr[8], fi[8];
#pragma unroll
        for (int j = 0; j < 8; ++j) {
            int e = k2 * 32 + (lane >> 4) * 8 + j;
            fr[j] = sQR[e * 65 + x];
            fi[j] = sQI[e * 65 + x];
        }
        make_hilo8(fr, aRh[k2], aRl[k2]);
        make_hilo8(fi, aIh[k2], aIl[k2]);
        aInh[k2] = neg8(aIh[k2]);
        aInl[k2] = neg8(aIl[k2]);
    }
    __syncthreads();   // all Xq reads done before S~ overwrites sQ

    // ---- GEMM1: S[x][y], K=e
    f32x4 Sr[4], Si[4];
#pragma unroll
    for (int c = 0; c < 4; ++c) { Sr[c] = (f32x4){0.f,0.f,0.f,0.f}; Si[c] = (f32x4){0.f,0.f,0.f,0.f}; }
#pragma unroll
    for (int k2 = 0; k2 < 2; ++k2) {
#pragma unroll
        for (int nt = 0; nt < 4; ++nt) {
            float gr[8], gi[8];
            int y = nt * 16 + (lane & 15);
#pragma unroll
            for (int j = 0; j < 8; ++j) {
                int e = k2 * 32 + (lane >> 4) * 8 + j;
                gr[j] = sKR[e * 65 + y];
                gi[j] = sKI[e * 65 + y];
            }
            bf16x8 bRh, bRl, bIh, bIl;
            make_hilo8(gr, bRh, bRl);
            make_hilo8(gi, bIh, bIl);
            MFMA3(aRh[k2], aRl[k2], bRh, bRl, Sr[nt]);
            MFMA3(aInh[k2], aInl[k2], bIh, bIl, Sr[nt]);
            MFMA3(aRh[k2], aRl[k2], bIh, bIl, Si[nt]);
            MFMA3(aIh[k2], aIl[k2], bRh, bRl, Si[nt]);
        }
    }
#pragma unroll
    for (int nt = 0; nt < 4; ++nt)
#pragma unroll
        for (int r = 0; r < 4; ++r) {
            Sr[nt][r] = tanhf(Sr[nt][r]);
            Si[nt][r] = tanhf(Si[nt][r]);
        }
    // write S~ [x][y] stride 65 into sQ region
#pragma unroll
    for (int nt = 0; nt < 4; ++nt) {
        int y = nt * 16 + (lane & 15);
        int xr0 = wv * 16 + (lane >> 4) * 4;
#pragma unroll
        for (int r = 0; r < 4; ++r) {
            sQR[(xr0 + r) * 65 + y] = Sr[nt][r];
            sQI[(xr0 + r) * 65 + y] = Si[nt][r];
        }
    }
    __syncthreads();

    // ---- GEMM2 A-frags: A[m=x][k=y] = S~[x][y]
    bf16x8 cRh[2], cRl[2], cIh[2], cIl[2], cInh[2], cInl[2];
#pragma unroll
    for (int k2 = 0; k2 < 2; ++k2) {
        float fr[8], fi[8];
#pragma unroll
        for (int j = 0; j < 8; ++j) {
            int y = k2 * 32 + (lane >> 4) * 8 + j;
            fr[j] = sQR[x * 65 + y];
            fi[j] = sQI[x * 65 + y];
        }
        make_hilo8(fr, cRh[k2], cRl[k2]);
        make_hilo8(fi, cIh[k2], cIl[k2]);
        cInh[k2] = neg8(cIh[k2]);
        cInl[k2] = neg8(cIl[k2]);
    }

    // ---- GEMM2: u[x][e] = sum_y S~[x][y] * Xk[e][y]  (B[k=y][n=e] = XkT)
    f32x4 Ur[4], Ui[4];
#pragma unroll
    for (int c = 0; c < 4; ++c) { Ur[c] = (f32x4){0.f,0.f,0.f,0.f}; Ui[c] = (f32x4){0.f,0.f,0.f,0.f}; }
#pragma unroll
    for (int k2 = 0; k2 < 2; ++k2) {
#pragma unroll
        for (int nt = 0; nt < 4; ++nt) {
            float gr[8], gi[8];
            int e = nt * 16 + (lane & 15);
#pragma unroll
            for (int j = 0; j < 8; ++j) {
                int y = k2 * 32 + (lane >> 4) * 8 + j;
                gr[j] = sKR[e * 65 + y];
                gi[j] = sKI[e * 65 + y];
            }
            bf16x8 bRh, bRl, bIh, bIl;
            make_hilo8(gr, bRh, bRl);
            make_hilo8(gi, bIh, bIl);
            MFMA3(cRh[k2], cRl[k2], bRh, bRl, Ur[nt]);
            MFMA3(cInh[k2], cInl[k2], bIh, bIl, Ur[nt]);
            MFMA3(cRh[k2], cRl[k2], bIh, bIl, Ui[nt]);
            MFMA3(cIh[k2], cIl[k2], bRh, bRl, Ui[nt]);
        }
    }
    // write u: [h][x][b][e]
    float* uRp = ws + OFF_UR;
    float* uIp = ws + OFF_UI;
#pragma unroll
    for (int nt = 0; nt < 4; ++nt) {
        int e = nt * 16 + (lane & 15);
        int xr0 = wv * 16 + (lane >> 4) * 4;
#pragma unroll
        for (int r = 0; r < 4; ++r) {
            size_t base = (((size_t)h * 64 + xr0 + r) * 32 + b) * 64 + e;
            uRp[base] = Ur[nt][r];
            uIp[base] = Ui[nt][r];
        }
    }
}

// ---------------- uw: Y[b][o] = sum_e u[b][e]*w[e][o]  per (h,x), MFMA ------
// grid 512 = hx; 256 threads, 4 waves; wave owns one o-tile (nt = wv).
__global__ __launch_bounds__(256, 2) void k_uw(float* __restrict__ ws) {
    int hx = blockIdx.x;
    int tid = threadIdx.x, lane = tid & 63, wv = tid >> 6;
    const float* uRp = ws + OFF_UR + (size_t)hx * 2048;
    const float* uIp = ws + OFF_UI + (size_t)hx * 2048;
    const float* wRp = ws + OFF_WTR + (size_t)hx * 4096;
    const float* wIp = ws + OFF_WTI + (size_t)hx * 4096;

    // A-frags: A[m=b][k=e] = u[b][e] (contiguous)
    bf16x8 aRh[2][2], aRl[2][2], aIh[2][2], aIl[2][2], aInh[2][2], aInl[2][2];
#pragma unroll
    for (int mt = 0; mt < 2; ++mt) {
        int bb = mt * 16 + (lane & 15);
#pragma unroll
        for (int k2 = 0; k2 < 2; ++k2) {
            int e0 = k2 * 32 + (lane >> 4) * 8;
            float fr[8], fi[8];
#pragma unroll
            for (int j = 0; j < 8; ++j) {
                fr[j] = uRp[bb * 64 + e0 + j];
                fi[j] = uIp[bb * 64 + e0 + j];
            }
            make_hilo8(fr, aRh[mt][k2], aRl[mt][k2]);
            make_hilo8(fi, aIh[mt][k2], aIl[mt][k2]);
            aInh[mt][k2] = neg8(aIh[mt][k2]);
            aInl[mt][k2] = neg8(aIl[mt][k2]);
        }
    }

    f32x4 Yr[2], Yi[2];
#pragma unroll
    for (int mt = 0; mt < 2; ++mt) { Yr[mt] = (f32x4){0.f,0.f,0.f,0.f}; Yi[mt] = (f32x4){0.f,0.f,0.f,0.f}; }
    int o = wv * 16 + (lane & 15);
#pragma unroll
    for (int k2 = 0; k2 < 2; ++k2) {
        float gr[8], gi[8];
#pragma unroll
        for (int j = 0; j < 8; ++j) {
            int e = k2 * 32 + (lane >> 4) * 8 + j;
            gr[j] = wRp[e * 64 + o];
            gi[j] = wIp[e * 64 + o];
        }
        bf16x8 bRh, bRl, bIh, bIl;
        make_hilo8(gr, bRh, bRl);
        make_hilo8(gi, bIh, bIl);
#pragma unroll
        for (int mt = 0; mt < 2; ++mt) {
            MFMA3(aRh[mt][k2], aRl[mt][k2], bRh, bRl, Yr[mt]);
            MFMA3(aInh[mt][k2], aInl[mt][k2], bIh, bIl, Yr[mt]);
            MFMA3(aRh[mt][k2], aRl[mt][k2], bIh, bIl, Yi[mt]);
            MFMA3(aIh[mt][k2], aIl[mt][k2], bRh, bRl, Yi[mt]);
        }
    }
    float* YRp = ws + OFF_YR + (size_t)hx * 2048;
    float* YIp = ws + OFF_YI + (size_t)hx * 2048;
#pragma unroll
    for (int mt = 0; mt < 2; ++mt) {
#pragma unroll
        for (int r = 0; r < 4; ++r) {
            int bb = mt * 16 + (lane >> 4) * 4 + r;
            YRp[bb * 64 + o] = Yr[mt][r];
            YIp[bb * 64 + o] = Yi[mt][r];
        }
    }
}

// ---------------- iDFT via MFMA: out[o][t] = Acoef[o][kap] * B[kap][t] ------
// grid 512 = (b,h) x nhalf. 512 threads, 8 waves; wave owns 4 n-tiles (64 t).
__global__ __launch_bounds__(512, 2) void k_idft(const float* __restrict__ ws,
                                                 float* __restrict__ out) {
    __shared__ float Acoef[64 * 132];   // [o][kap], row stride 132
    int blk = blockIdx.x;
    int bhi = blk >> 1, nhf = blk & 1;
    int b = bhi >> 3, h = bhi & 7;
    int tid = threadIdx.x;
    int lane = tid & 63, wv = tid >> 6;
    const float S0 = 3.7252902984619140625e-09f;   // 1/2^28
    const float* YRp = ws + OFF_YR;
    const float* YIp = ws + OFF_YI;
    const unsigned short* BIH = (const unsigned short*)ws + 262144;
    const unsigned short* BIL = (const unsigned short*)ws + 393216;

    for (int i = tid; i < 4096; i += 512) {
        int m = i >> 6, o = i & 63;
        size_t src = ((size_t)h * 64 + m) * 2048 + (size_t)b * 64 + o;
        float sca = (m == 0 ? 1.f : 2.f) * S0;
        Acoef[o * 132 + m] = YRp[src] * sca;
        Acoef[o * 132 + 64 + m] = YIp[src] * sca;
    }
    __syncthreads();

    bf16x8 ah[4][4], al[4][4];
#pragma unroll
    for (int mt = 0; mt < 4; ++mt)
#pragma unroll
        for (int ks = 0; ks < 4; ++ks) {
            int o = mt * 16 + (lane & 15);
            int kap0 = ks * 32 + (lane >> 4) * 8;
            float4 p0 = *(const float4*)&Acoef[o * 132 + kap0];
            float4 p1 = *(const float4*)&Acoef[o * 132 + kap0 + 4];
            float f[8] = { p0.x, p0.y, p0.z, p0.w, p1.x, p1.y, p1.z, p1.w };
            make_hilo8(f, ah[mt][ks], al[mt][ks]);
        }

    float* outp = out + ((size_t)b * 8 + h) * 65536;
#pragma unroll 2
    for (int ntl = 0; ntl < 4; ++ntl) {
        int nt = nhf * 32 + wv * 4 + ntl;
        f32x4 acc[4];
#pragma unroll
        for (int mt = 0; mt < 4; ++mt) acc[mt] = (f32x4){0.f, 0.f, 0.f, 0.f};
#pragma unroll
        for (int ks = 0; ks < 4; ++ks) {
            size_t off = (((size_t)nt * 4 + ks) * 64 + lane) * 8;
            bf16x8 tbh = *(const bf16x8*)(BIH + off);
            bf16x8 tbl = *(const bf16x8*)(BIL + off);
#pragma unroll
            for (int mt = 0; mt < 4; ++mt) {
                MFMA3(ah[mt][ks], al[mt][ks], tbh, tbl, acc[mt]);
            }
        }
        int t = nt * 16 + (lane & 15);
#pragma unroll
        for (int mt = 0; mt < 4; ++mt) {
            int o0 = mt * 16 + (lane >> 4) * 4;
#pragma unroll
            for (int r = 0; r < 4; ++r)
                outp[(size_t)(o0 + r) * 1024 + t] = acc[mt][r];
        }
    }
}

extern "C" void kernel_launch(void* const* d_in, const int* in_sizes, int n_in,
                              void* d_out, int out_size, void* d_ws, size_t ws_size,
                              hipStream_t stream) {
    const float* q = (const float*)d_in[0];
    const float* k = (const float*)d_in[1];
    const float* wr = (const float*)d_in[4];
    const float* wi = (const float*)d_in[5];
    float* out = (float*)d_out;
    float* ws = (float*)d_ws;   // needs 51.4 MB

    k_tables<<<512, 256, 0, stream>>>((unsigned short*)d_ws);
    k_wt<<<512, 256, 0, stream>>>(wr, wi, ws);
    k_dft<<<512, 512, 0, stream>>>(q, k, ws);
    k_attn<<<256, 256, 0, stream>>>(ws);
    k_uw<<<512, 256, 0, stream>>>(ws);
    k_idft<<<512, 512, 0, stream>>>(ws, out);
}

// Round 4
// 309.869 us; speedup vs baseline: 1.3102x; 1.3102x over previous
//
#include <hip/hip_runtime.h>
#include <math.h>

// FourierCrossAttention, MI355X. Round 7: k_dft rebuilt with LDS staging —
// coalesced float4 global loads into a double-buffered [128t][66-stride] LDS
// tile (T14 issue-early/write-late split, sched_barrier pin), MFMA frags read
// from LDS (2-way-free banking). All other kernels = round-0 verified source.
// R3 lesson: register ping-pong prefetch gets defeated by regalloc (VGPR 64).
// R2 lesson: v_cvt_pk_bf16_f32 truncates -> keep RNE bit-twiddle make_hilo8.
// B=32 H=8 E=64 M=64 O=64 L=1024.
//
// ws layout:
//   bytes [0, 1MB): bf16 twiddle tables in MFMA B-fragment layout (hi/lo)
//   floats from 262144: as before.
#define OFF_WTR   262144u   // wT[h][x][e][o]  2097152
#define OFF_WTI   2359296u
#define OFF_XQR   4456448u  // Xq [b][h][e][m] 1048576
#define OFF_XQI   5505024u
#define OFF_XKR   6553600u
#define OFF_XKI   7602176u
#define OFF_UR    8650752u  // u  [h][x][b][e] 1048576
#define OFF_UI    9699328u
#define OFF_YR    10747904u // xqkvw [h][x][b][o] 1048576
#define OFF_YI    11796480u

#define PI_F 3.14159265358979323846f

typedef __attribute__((ext_vector_type(8))) short bf16x8;
typedef __attribute__((ext_vector_type(4))) float f32x4;

__device__ inline unsigned short f2bf(float f) {
    unsigned u = __float_as_uint(f);
    unsigned r = u + 0x7FFFu + ((u >> 16) & 1u);
    return (unsigned short)(r >> 16);
}
__device__ inline float bf2f(unsigned short h) {
    return __uint_as_float(((unsigned)h) << 16);
}
// Verified RNE hi/lo split (absmax 7.3e-12). Do NOT replace with
// v_cvt_pk_bf16_f32: it does not round-to-nearest here (R2: 51x error).
__device__ inline void make_hilo8(const float* s, bf16x8& h, bf16x8& l) {
#pragma unroll
    for (int j = 0; j < 8; ++j) {
        unsigned short hb = f2bf(s[j]);
        h[j] = (short)hb;
        l[j] = (short)f2bf(s[j] - bf2f(hb));
    }
}
__device__ inline bf16x8 neg8(bf16x8 v) {
    bf16x8 r;
#pragma unroll
    for (int j = 0; j < 8; ++j) r[j] = (short)(((unsigned short)v[j]) ^ 0x8000u);
    return r;
}
__device__ inline float twval(int m, int t, bool neg_sin) {
    int r = (m * t) & 1023;
    float ang = (float)r * (2.0f * PI_F / 1024.0f);
    float s, c;
    sincosf(ang, &s, &c);
    return neg_sin ? -s : c;
}

// 3-pass split-bf16 MFMA: acc += (Ah+Al)*(Bh+Bl) approx
#define MFMA3(AH, AL, BH, BL, ACC)                                          \
    ACC = __builtin_amdgcn_mfma_f32_16x16x32_bf16(AH, BH, ACC, 0, 0, 0);    \
    ACC = __builtin_amdgcn_mfma_f32_16x16x32_bf16(AH, BL, ACC, 0, 0, 0);    \
    ACC = __builtin_amdgcn_mfma_f32_16x16x32_bf16(AL, BH, ACC, 0, 0, 0);

// ---------------- twiddle tables in MFMA B-fragment layout, split hi/lo -----
__global__ void k_tables(unsigned short* __restrict__ tab) {
    int idx = blockIdx.x * 256 + threadIdx.x;   // 131072 entries each table
    {
        int j = idx & 7, lane = (idx >> 3) & 63, nt = (idx >> 9) & 7, kt = idx >> 12;
        int k = kt * 32 + ((lane >> 4) << 3) + j;       // t (K dim)
        int n = nt * 16 + (lane & 15);                  // col in [0,128)
        float v = twval(n & 63, k, n >= 64);
        unsigned short hb = f2bf(v);
        tab[idx] = hb;
        tab[131072 + idx] = f2bf(v - bf2f(hb));
    }
    {
        int j = idx & 7, lane = (idx >> 3) & 63, ks = (idx >> 9) & 3, nt = idx >> 11;
        int kap = ks * 32 + ((lane >> 4) << 3) + j;     // kappa in [0,128)
        int t = nt * 16 + (lane & 15);
        float v = twval(kap & 63, t, kap >= 64);
        unsigned short hb = f2bf(v);
        tab[262144 + idx] = hb;
        tab[393216 + idx] = f2bf(v - bf2f(hb));
    }
}

// ---------------- transpose weights [h][e][o][x] -> [h][x][e][o] ------------
__global__ __launch_bounds__(256) void k_wt(const float* __restrict__ wr,
                                            const float* __restrict__ wi,
                                            float* __restrict__ ws) {
    __shared__ float tile[64 * 65];
    int he = blockIdx.x;            // h*64+e
    int h = he >> 6, e = he & 63;
    const float* srcs[2] = { wr + (size_t)he * 4096, wi + (size_t)he * 4096 };
    float* dsts[2] = { ws + OFF_WTR, ws + OFF_WTI };
    for (int p = 0; p < 2; ++p) {
        __syncthreads();
        {
            int x = threadIdx.x & 63, orow = threadIdx.x >> 6;
            for (int i = 0; i < 16; ++i) {
                int o = orow * 16 + i;
                tile[o * 65 + x] = srcs[p][o * 64 + x];
            }
        }
        __syncthreads();
        {
            int o = threadIdx.x & 63, xrow = threadIdx.x >> 6;
            for (int i = 0; i < 16; ++i) {
                int x = xrow * 16 + i;
                dsts[p][(((size_t)h * 64 + x) * 64 + e) * 64 + o] = tile[o * 65 + x];
            }
        }
    }
}

// ---------------- DFT via MFMA, LDS-staged double-buffered K-loop -----------
// grid 512: src*256 + bh. 512 threads, 8 waves = 2 khalf x 2 mhalf x 2 nhalf.
// Per kc: chunk [128 t][64 e] f32 staged in LDS (row stride 66 -> frag reads
// are 2-way bank aliasing = free). Global loads: float4, 256B-contiguous rows.
// T14 split: issue loads for kc+1 FIRST, pin with sched_barrier(0), compute
// kc from LDS, then ds_write the staged regs, one barrier per kc.
__global__ __launch_bounds__(512, 4) void k_dft(const float* __restrict__ q,
                                                const float* __restrict__ kk,
                                                float* __restrict__ ws) {
    __shared__ float smem[2 * 128 * 66];   // 67.6 KB stage dbuf; red aliases
    int blk = blockIdx.x;
    int src = blk >> 8;
    int bhi = blk & 255;
    int b = bhi >> 3, h = bhi & 7;
    const float* A = src ? kk : q;
    const unsigned short* BDH = (const unsigned short*)ws;
    const unsigned short* BDL = BDH + 131072;

    int tid = threadIdx.x;
    int lane = tid & 63, wv = tid >> 6;
    int kh = wv & 1, mh = (wv >> 1) & 1, nh = wv >> 2;

    const float* Ab = A + ((size_t)b * 1024 * 8 + h) * 64;
    int srow = tid >> 4;             // 0..31: staging row within 32-row group
    int se4 = (tid & 15) * 4;        // e offset (float4 granule)

    f32x4 acc[2][4];
#pragma unroll
    for (int a = 0; a < 2; ++a)
#pragma unroll
        for (int c = 0; c < 4; ++c) acc[a][c] = (f32x4){0.f, 0.f, 0.f, 0.f};

    // prologue: stage chunk kc=0 into buffer 0
    {
        float4 v0 = *(const float4*)(Ab + (size_t)(srow      ) * 512 + se4);
        float4 v1 = *(const float4*)(Ab + (size_t)(srow +  32) * 512 + se4);
        float4 v2 = *(const float4*)(Ab + (size_t)(srow + 512) * 512 + se4);
        float4 v3 = *(const float4*)(Ab + (size_t)(srow + 544) * 512 + se4);
        float* p0 = smem + (srow     ) * 66 + se4;
        float* p1 = smem + (srow + 32) * 66 + se4;
        float* p2 = smem + (srow + 64) * 66 + se4;
        float* p3 = smem + (srow + 96) * 66 + se4;
        *(float2*)p0 = make_float2(v0.x, v0.y); *(float2*)(p0 + 2) = make_float2(v0.z, v0.w);
        *(float2*)p1 = make_float2(v1.x, v1.y); *(float2*)(p1 + 2) = make_float2(v1.z, v1.w);
        *(float2*)p2 = make_float2(v2.x, v2.y); *(float2*)(p2 + 2) = make_float2(v2.z, v2.w);
        *(float2*)p3 = make_float2(v3.x, v3.y); *(float2*)(p3 + 2) = make_float2(v3.z, v3.w);
    }
    __syncthreads();

    for (int kc = 0; kc < 8; ++kc) {
        int cur = kc & 1, nxt = cur ^ 1;
        float4 v0, v1, v2, v3;
        if (kc < 7) {   // issue next-chunk loads EARLY (latency hides under compute)
            const float* An = Ab + (size_t)(kc + 1) * 64 * 512;
            v0 = *(const float4*)(An + (size_t)(srow      ) * 512 + se4);
            v1 = *(const float4*)(An + (size_t)(srow +  32) * 512 + se4);
            v2 = *(const float4*)(An + (size_t)(srow + 512) * 512 + se4);
            v3 = *(const float4*)(An + (size_t)(srow + 544) * 512 + se4);
        }
        __builtin_amdgcn_sched_barrier(0);   // pin the loads before compute

        const float* S = smem + cur * 8448;
        bf16x8 ah[2][2], al[2][2];
#pragma unroll
        for (int mt = 0; mt < 2; ++mt) {
            int e = mh * 32 + mt * 16 + (lane & 15);
#pragma unroll
            for (int k2 = 0; k2 < 2; ++k2) {
                int r0 = kh * 64 + k2 * 32 + ((lane >> 4) << 3);
                float f[8];
#pragma unroll
                for (int j = 0; j < 8; ++j) f[j] = S[(r0 + j) * 66 + e];
                make_hilo8(f, ah[mt][k2], al[mt][k2]);
            }
        }
#pragma unroll
        for (int k2 = 0; k2 < 2; ++k2) {
            int ktile = kh * 16 + kc * 2 + k2;
#pragma unroll
            for (int ntl = 0; ntl < 4; ++ntl) {
                int nt = nh * 4 + ntl;
                size_t off = (((size_t)ktile * 8 + nt) * 64 + lane) * 8;
                bf16x8 tbh = *(const bf16x8*)(BDH + off);
                bf16x8 tbl = *(const bf16x8*)(BDL + off);
#pragma unroll
                for (int mt = 0; mt < 2; ++mt) {
                    MFMA3(ah[mt][k2], al[mt][k2], tbh, tbl, acc[mt][ntl]);
                }
            }
        }
        if (kc < 7) {   // write staged regs LATE (vmcnt wait lands here)
            float* W = smem + nxt * 8448;
            float* p0 = W + (srow     ) * 66 + se4;
            float* p1 = W + (srow + 32) * 66 + se4;
            float* p2 = W + (srow + 64) * 66 + se4;
            float* p3 = W + (srow + 96) * 66 + se4;
            *(float2*)p0 = make_float2(v0.x, v0.y); *(float2*)(p0 + 2) = make_float2(v0.z, v0.w);
            *(float2*)p1 = make_float2(v1.x, v1.y); *(float2*)(p1 + 2) = make_float2(v1.z, v1.w);
            *(float2*)p2 = make_float2(v2.x, v2.y); *(float2*)(p2 + 2) = make_float2(v2.z, v2.w);
            *(float2*)p3 = make_float2(v3.x, v3.y); *(float2*)(p3 + 2) = make_float2(v3.z, v3.w);
        }
        __syncthreads();
    }

    // khalf reduction; red aliases smem[0..8191] (all stage reads done after
    // the final loop barrier).
    int pair = wv >> 1;   // mh + 2*nh
    if (kh == 1) {
#pragma unroll
        for (int mt = 0; mt < 2; ++mt)
#pragma unroll
            for (int ntl = 0; ntl < 4; ++ntl)
#pragma unroll
                for (int r = 0; r < 4; ++r)
                    smem[pair * 2048 + ((mt * 4 + ntl) * 4 + r) * 64 + lane] = acc[mt][ntl][r];
    }
    __syncthreads();
    if (kh == 0) {
        float* outR = ws + (src ? OFF_XKR : OFF_XQR) + (size_t)bhi * 4096;
        float* outI = ws + (src ? OFF_XKI : OFF_XQI) + (size_t)bhi * 4096;
#pragma unroll
        for (int mt = 0; mt < 2; ++mt)
#pragma unroll
            for (int ntl = 0; ntl < 4; ++ntl) {
#pragma unroll
                for (int r = 0; r < 4; ++r)
                    acc[mt][ntl][r] += smem[pair * 2048 + ((mt * 4 + ntl) * 4 + r) * 64 + lane];
                int n = (nh * 4 + ntl) * 16 + (lane & 15);
                float* dst = (n < 64) ? (outR + n) : (outI + (n - 64));
                int erow0 = mh * 32 + mt * 16 + (lane >> 4) * 4;
#pragma unroll
                for (int r = 0; r < 4; ++r)
                    dst[(erow0 + r) * 64] = acc[mt][ntl][r];
            }
    }
}

// ---------------- attn: S = Xq^T Xk, tanh, u = S~ Xk^T, all MFMA ------------
// grid 256 = (b,h); 256 threads, 4 waves; wave owns 16 rows (x).
__global__ __launch_bounds__(256, 1) void k_attn(float* __restrict__ ws) {
    __shared__ float sKR[64 * 65], sKI[64 * 65];
    __shared__ float sQR[64 * 65], sQI[64 * 65];   // later reused for S~
    int bhi = blockIdx.x;
    int b = bhi >> 3, h = bhi & 7;
    int tid = threadIdx.x, lane = tid & 63, wv = tid >> 6;
    const float* XqR = ws + OFF_XQR + (size_t)bhi * 4096;
    const float* XqI = ws + OFF_XQI + (size_t)bhi * 4096;
    const float* XkR = ws + OFF_XKR + (size_t)bhi * 4096;
    const float* XkI = ws + OFF_XKI + (size_t)bhi * 4096;
    for (int i = tid; i < 4096; i += 256) {
        int e = i >> 6, m = i & 63;
        sQR[e * 65 + m] = XqR[i];
        sQI[e * 65 + m] = XqI[i];
        sKR[e * 65 + m] = XkR[i];
        sKI[e * 65 + m] = XkI[i];
    }
    __syncthreads();

    // ---- GEMM1 A-frags: A[m=x][k=e] = Xq[e][x]
    int x = wv * 16 + (lane & 15);
    bf16x8 aRh[2], aRl[2], aIh[2], aIl[2], aInh[2], aInl[2];
#pragma unroll
    for (int k2 = 0; k2 < 2; ++k2) {
        float fr[8], fi[8];
#pragma unroll
        for (int j = 0; j < 8; ++j) {
            int e = k2 * 32 + (lane >> 4) * 8 + j;
            fr[j] = sQR[e * 65 + x];
            fi[j] = sQI[e * 65 + x];
        }
        make_hilo8(fr, aRh[k2], aRl[k2]);
        make_hilo8(fi, aIh[k2], aIl[k2]);
        aInh[k2] = neg8(aIh[k2]);
        aInl[k2] = neg8(aIl[k2]);
    }
    __syncthreads();   // all Xq reads done before S~ overwrites sQ

    // ---- GEMM1: S[x][y], K=e
    f32x4 Sr[4], Si[4];
#pragma unroll
    for (int c = 0; c < 4; ++c) { Sr[c] = (f32x4){0.f,0.f,0.f,0.f}; Si[c] = (f32x4){0.f,0.f,0.f,0.f}; }
#pragma unroll
    for (int k2 = 0; k2 < 2; ++k2) {
#pragma unroll
        for (int nt = 0; nt < 4; ++nt) {
            float gr[8], gi[8];
            int y = nt * 16 + (lane & 15);
#pragma unroll
            for (int j = 0; j < 8; ++j) {
                int e = k2 * 32 + (lane >> 4) * 8 + j;
                gr[j] = sKR[e * 65 + y];
                gi[j] = sKI[e * 65 + y];
            }
            bf16x8 bRh, bRl, bIh, bIl;
            make_hilo8(gr, bRh, bRl);
            make_hilo8(gi, bIh, bIl);
            MFMA3(aRh[k2], aRl[k2], bRh, bRl, Sr[nt]);
            MFMA3(aInh[k2], aInl[k2], bIh, bIl, Sr[nt]);
            MFMA3(aRh[k2], aRl[k2], bIh, bIl, Si[nt]);
            MFMA3(aIh[k2], aIl[k2], bRh, bRl, Si[nt]);
        }
    }
#pragma unroll
    for (int nt = 0; nt < 4; ++nt)
#pragma unroll
        for (int r = 0; r < 4; ++r) {
            Sr[nt][r] = tanhf(Sr[nt][r]);
            Si[nt][r] = tanhf(Si[nt][r]);
        }
    // write S~ [x][y] stride 65 into sQ region
#pragma unroll
    for (int nt = 0; nt < 4; ++nt) {
        int y = nt * 16 + (lane & 15);
        int xr0 = wv * 16 + (lane >> 4) * 4;
#pragma unroll
        for (int r = 0; r < 4; ++r) {
            sQR[(xr0 + r) * 65 + y] = Sr[nt][r];
            sQI[(xr0 + r) * 65 + y] = Si[nt][r];
        }
    }
    __syncthreads();

    // ---- GEMM2 A-frags: A[m=x][k=y] = S~[x][y]
    bf16x8 cRh[2], cRl[2], cIh[2], cIl[2], cInh[2], cInl[2];
#pragma unroll
    for (int k2 = 0; k2 < 2; ++k2) {
        float fr[8], fi[8];
#pragma unroll
        for (int j = 0; j < 8; ++j) {
            int y = k2 * 32 + (lane >> 4) * 8 + j;
            fr[j] = sQR[x * 65 + y];
            fi[j] = sQI[x * 65 + y];
        }
        make_hilo8(fr, cRh[k2], cRl[k2]);
        make_hilo8(fi, cIh[k2], cIl[k2]);
        cInh[k2] = neg8(cIh[k2]);
        cInl[k2] = neg8(cIl[k2]);
    }

    // ---- GEMM2: u[x][e] = sum_y S~[x][y] * Xk[e][y]  (B[k=y][n=e] = XkT)
    f32x4 Ur[4], Ui[4];
#pragma unroll
    for (int c = 0; c < 4; ++c) { Ur[c] = (f32x4){0.f,0.f,0.f,0.f}; Ui[c] = (f32x4){0.f,0.f,0.f,0.f}; }
#pragma unroll
    for (int k2 = 0; k2 < 2; ++k2) {
#pragma unroll
        for (int nt = 0; nt < 4; ++nt) {
            float gr[8], gi[8];
            int e = nt * 16 + (lane & 15);
#pragma unroll
            for (int j = 0; j < 8; ++j) {
                int y = k2 * 32 + (lane >> 4) * 8 + j;
                gr[j] = sKR[e * 65 + y];
                gi[j] = sKI[e * 65 + y];
            }
            bf16x8 bRh, bRl, bIh, bIl;
            make_hilo8(gr, bRh, bRl);
            make_hilo8(gi, bIh, bIl);
            MFMA3(cRh[k2], cRl[k2], bRh, bRl, Ur[nt]);
            MFMA3(cInh[k2], cInl[k2], bIh, bIl, Ur[nt]);
            MFMA3(cRh[k2], cRl[k2], bIh, bIl, Ui[nt]);
            MFMA3(cIh[k2], cIl[k2], bRh, bRl, Ui[nt]);
        }
    }
    // write u: [h][x][b][e]
    float* uRp = ws + OFF_UR;
    float* uIp = ws + OFF_UI;
#pragma unroll
    for (int nt = 0; nt < 4; ++nt) {
        int e = nt * 16 + (lane & 15);
        int xr0 = wv * 16 + (lane >> 4) * 4;
#pragma unroll
        for (int r = 0; r < 4; ++r) {
            size_t base = (((size_t)h * 64 + xr0 + r) * 32 + b) * 64 + e;
            uRp[base] = Ur[nt][r];
            uIp[base] = Ui[nt][r];
        }
    }
}

// ---------------- uw: Y[b][o] = sum_e u[b][e]*w[e][o]  per (h,x), MFMA ------
// grid 512 = hx; 256 threads, 4 waves; wave owns one o-tile (nt = wv).
__global__ __launch_bounds__(256, 2) void k_uw(float* __restrict__ ws) {
    int hx = blockIdx.x;
    int tid = threadIdx.x, lane = tid & 63, wv = tid >> 6;
    const float* uRp = ws + OFF_UR + (size_t)hx * 2048;
    const float* uIp = ws + OFF_UI + (size_t)hx * 2048;
    const float* wRp = ws + OFF_WTR + (size_t)hx * 4096;
    const float* wIp = ws + OFF_WTI + (size_t)hx * 4096;

    // A-frags: A[m=b][k=e] = u[b][e] (contiguous)
    bf16x8 aRh[2][2], aRl[2][2], aIh[2][2], aIl[2][2], aInh[2][2], aInl[2][2];
#pragma unroll
    for (int mt = 0; mt < 2; ++mt) {
        int bb = mt * 16 + (lane & 15);
#pragma unroll
        for (int k2 = 0; k2 < 2; ++k2) {
            int e0 = k2 * 32 + (lane >> 4) * 8;
            float fr[8], fi[8];
#pragma unroll
            for (int j = 0; j < 8; ++j) {
                fr[j] = uRp[bb * 64 + e0 + j];
                fi[j] = uIp[bb * 64 + e0 + j];
            }
            make_hilo8(fr, aRh[mt][k2], aRl[mt][k2]);
            make_hilo8(fi, aIh[mt][k2], aIl[mt][k2]);
            aInh[mt][k2] = neg8(aIh[mt][k2]);
            aInl[mt][k2] = neg8(aIl[mt][k2]);
        }
    }

    f32x4 Yr[2], Yi[2];
#pragma unroll
    for (int mt = 0; mt < 2; ++mt) { Yr[mt] = (f32x4){0.f,0.f,0.f,0.f}; Yi[mt] = (f32x4){0.f,0.f,0.f,0.f}; }
    int o = wv * 16 + (lane & 15);
#pragma unroll
    for (int k2 = 0; k2 < 2; ++k2) {
        float gr[8], gi[8];
#pragma unroll
        for (int j = 0; j < 8; ++j) {
            int e = k2 * 32 + (lane >> 4) * 8 + j;
            gr[j] = wRp[e * 64 + o];
            gi[j] = wIp[e * 64 + o];
        }
        bf16x8 bRh, bRl, bIh, bIl;
        make_hilo8(gr, bRh, bRl);
        make_hilo8(gi, bIh, bIl);
#pragma unroll
        for (int mt = 0; mt < 2; ++mt) {
            MFMA3(aRh[mt][k2], aRl[mt][k2], bRh, bRl, Yr[mt]);
            MFMA3(aInh[mt][k2], aInl[mt][k2], bIh, bIl, Yr[mt]);
            MFMA3(aRh[mt][k2], aRl[mt][k2], bIh, bIl, Yi[mt]);
            MFMA3(aIh[mt][k2], aIl[mt][k2], bRh, bRl, Yi[mt]);
        }
    }
    float* YRp = ws + OFF_YR + (size_t)hx * 2048;
    float* YIp = ws + OFF_YI + (size_t)hx * 2048;
#pragma unroll
    for (int mt = 0; mt < 2; ++mt) {
#pragma unroll
        for (int r = 0; r < 4; ++r) {
            int bb = mt * 16 + (lane >> 4) * 4 + r;
            YRp[bb * 64 + o] = Yr[mt][r];
            YIp[bb * 64 + o] = Yi[mt][r];
        }
    }
}

// ---------------- iDFT via MFMA: out[o][t] = Acoef[o][kap] * B[kap][t] ------
// grid 512 = (b,h) x nhalf. 512 threads, 8 waves; wave owns 4 n-tiles (64 t).
__global__ __launch_bounds__(512, 2) void k_idft(const float* __restrict__ ws,
                                                 float* __restrict__ out) {
    __shared__ float Acoef[64 * 132];   // [o][kap], row stride 132
    int blk = blockIdx.x;
    int bhi = blk >> 1, nhf = blk & 1;
    int b = bhi >> 3, h = bhi & 7;
    int tid = threadIdx.x;
    int lane = tid & 63, wv = tid >> 6;
    const float S0 = 3.7252902984619140625e-09f;   // 1/2^28
    const float* YRp = ws + OFF_YR;
    const float* YIp = ws + OFF_YI;
    const unsigned short* BIH = (const unsigned short*)ws + 262144;
    const unsigned short* BIL = (const unsigned short*)ws + 393216;

    for (int i = tid; i < 4096; i += 512) {
        int m = i >> 6, o = i & 63;
        size_t src = ((size_t)h * 64 + m) * 2048 + (size_t)b * 64 + o;
        float sca = (m == 0 ? 1.f : 2.f) * S0;
        Acoef[o * 132 + m] = YRp[src] * sca;
        Acoef[o * 132 + 64 + m] = YIp[src] * sca;
    }
    __syncthreads();

    bf16x8 ah[4][4], al[4][4];
#pragma unroll
    for (int mt = 0; mt < 4; ++mt)
#pragma unroll
        for (int ks = 0; ks < 4; ++ks) {
            int o = mt * 16 + (lane & 15);
            int kap0 = ks * 32 + (lane >> 4) * 8;
            float4 p0 = *(const float4*)&Acoef[o * 132 + kap0];
            float4 p1 = *(const float4*)&Acoef[o * 132 + kap0 + 4];
            float f[8] = { p0.x, p0.y, p0.z, p0.w, p1.x, p1.y, p1.z, p1.w };
            make_hilo8(f, ah[mt][ks], al[mt][ks]);
        }

    float* outp = out + ((size_t)b * 8 + h) * 65536;
#pragma unroll 2
    for (int ntl = 0; ntl < 4; ++ntl) {
        int nt = nhf * 32 + wv * 4 + ntl;
        f32x4 acc[4];
#pragma unroll
        for (int mt = 0; mt < 4; ++mt) acc[mt] = (f32x4){0.f, 0.f, 0.f, 0.f};
#pragma unroll
        for (int ks = 0; ks < 4; ++ks) {
            size_t off = (((size_t)nt * 4 + ks) * 64 + lane) * 8;
            bf16x8 tbh = *(const bf16x8*)(BIH + off);
            bf16x8 tbl = *(const bf16x8*)(BIL + off);
#pragma unroll
            for (int mt = 0; mt < 4; ++mt) {
                MFMA3(ah[mt][ks], al[mt][ks], tbh, tbl, acc[mt]);
            }
        }
        int t = nt * 16 + (lane & 15);
#pragma unroll
        for (int mt = 0; mt < 4; ++mt) {
            int o0 = mt * 16 + (lane >> 4) * 4;
#pragma unroll
            for (int r = 0; r < 4; ++r)
                outp[(size_t)(o0 + r) * 1024 + t] = acc[mt][r];
        }
    }
}

extern "C" void kernel_launch(void* const* d_in, const int* in_sizes, int n_in,
                              void* d_out, int out_size, void* d_ws, size_t ws_size,
                              hipStream_t stream) {
    const float* q = (const float*)d_in[0];
    const float* k = (const float*)d_in[1];
    const float* wr = (const float*)d_in[4];
    const float* wi = (const float*)d_in[5];
    float* out = (float*)d_out;
    float* ws = (float*)d_ws;   // needs 51.4 MB

    k_tables<<<512, 256, 0, stream>>>((unsigned short*)d_ws);
    k_wt<<<512, 256, 0, stream>>>(wr, wi, ws);
    k_dft<<<512, 512, 0, stream>>>(q, k, ws);
    k_attn<<<256, 256, 0, stream>>>(ws);
    k_uw<<<512, 256, 0, stream>>>(ws);
    k_idft<<<512, 512, 0, stream>>>(ws, out);
}